// Round 2
// baseline (69599.438 us; speedup 1.0000x reference)
//
#include <hip/hip_runtime.h>

#define Bn 32
#define Sn 64
#define Tn 64
#define Hn 512
#define Vn 32000

// ---- workspace layout (float offsets) ----
#define KP_OFF   0u            // keys_proj: 2048*512 = 1048576
#define H0_OFF   1048576u      // h buffer 0: 16384
#define H1_OFF   1064960u      // h buffer 1: 16384
#define CTX_OFF  1081344u      // context: 16384
#define QB_OFF   1097728u      // q = Wa@h: 16384
#define PK_OFF   1114112u      // packed argmax: 64*32 ull = 4096 float slots (8B aligned)
#define TOK_OFF  1118208u      // tok: 32 int
#define DONE_OFF 1118240u      // done counters: 64 uint

__device__ __forceinline__ float tanh_fast(float x) {
  return 1.f - 2.f / (__expf(2.f * x) + 1.f);
}
__device__ __forceinline__ float sigmoid_fast(float x) {
  return 1.f / (1.f + __expf(-x));
}
__device__ __forceinline__ float dot4(float4 a, float4 b) {
  return a.x * b.x + a.y * b.y + a.z * b.z + a.w * b.w;
}

// ---------------- keys_proj = einsum('bsh,gh->bsg', enc, Ua_w) + Ua_b ----------------
__global__ void __launch_bounds__(256) kp_kernel(const float* __restrict__ enc,
                                                 const float* __restrict__ Ua_w,
                                                 const float* __restrict__ Ua_b,
                                                 float* __restrict__ kp) {
  __shared__ __align__(16) float ea[32][68];
  __shared__ __align__(16) float ua[64][68];
  const int tid = threadIdx.x;
  const int bs0 = blockIdx.x * 32, g0 = blockIdx.y * 64;
  const int g_l = tid & 63;
  const int wv  = tid >> 6;
  float acc[8];
#pragma unroll
  for (int r = 0; r < 8; r++) acc[r] = 0.f;
  for (int kc = 0; kc < 8; kc++) {
    const int k0 = kc * 64;
    __syncthreads();
#pragma unroll
    for (int r = 0; r < 8; r++) { int f = tid + r * 256; int b = f >> 6, k = f & 63;
      ea[b][k] = enc[(bs0 + b) * Hn + k0 + k]; }
#pragma unroll
    for (int r = 0; r < 16; r++) { int f = tid + r * 256; int g = f >> 6, k = f & 63;
      ua[g][k] = Ua_w[(g0 + g) * Hn + k0 + k]; }
    __syncthreads();
#pragma unroll
    for (int kk = 0; kk < 16; kk++) {
      float4 u4 = *(const float4*)&ua[g_l][kk * 4];
#pragma unroll
      for (int r = 0; r < 8; r++) {
        float4 e4 = *(const float4*)&ea[wv + 4 * r][kk * 4];
        acc[r] += dot4(u4, e4);
      }
    }
  }
  const float bias = Ua_b[g0 + g_l];
#pragma unroll
  for (int r = 0; r < 8; r++) {
    int bs = bs0 + wv + 4 * r;
    kp[bs * Hn + g0 + g_l] = acc[r] + bias;
  }
}

// ---------------- init: q0 (blocks 0..63), state (block 64) ----------------
__global__ void __launch_bounds__(256) init_kernel(const float* __restrict__ eh,
                                                   const int* __restrict__ sos,
                                                   const float* __restrict__ Wa_w,
                                                   const float* __restrict__ Wa_b,
                                                   float* __restrict__ h0,
                                                   float* __restrict__ q0,
                                                   unsigned long long* __restrict__ packed,
                                                   int* __restrict__ tok,
                                                   unsigned int* __restrict__ done) {
  const int tid = threadIdx.x;
  if (blockIdx.x == 64) {
    for (int i = tid; i < Bn * Hn; i += 256) h0[i] = eh[i];
    if (tid < Bn) tok[tid] = sos[0];
    for (int i = tid; i < Tn * Bn; i += 256) packed[i] = 0ull;
    if (tid < Tn) done[tid] = 0u;
    return;
  }
  // q0[b, r] = Wa[r,:] . eh[b,:] + Wa_b[r]
  const int b = tid & 31, rh = tid >> 5;
  const int r = blockIdx.x * 8 + rh;
  const float4* w  = (const float4*)&Wa_w[r * Hn];
  const float4* hv = (const float4*)&eh[b * Hn];
  float a0 = 0.f, a1 = 0.f;
#pragma unroll 4
  for (int k4 = 0; k4 < 128; k4 += 2) {
    a0 += dot4(w[k4], hv[k4]);
    a1 += dot4(w[k4 + 1], hv[k4 + 1]);
  }
  q0[b * Hn + r] = a0 + a1 + Wa_b[r];
}

// ---------------- attention: scores(tanh), softmax, context. 32 blocks x 1024 ----------------
__global__ void __launch_bounds__(1024) attn_kernel(const float* __restrict__ enc,
                                                    const float* __restrict__ kp,
                                                    const float* __restrict__ Va_w,
                                                    const float* __restrict__ Va_b,
                                                    const float* __restrict__ qb_g,
                                                    float* __restrict__ ctx,
                                                    float* __restrict__ attn_out,
                                                    int t) {
  __shared__ __align__(16) float qv[Hn];
  __shared__ __align__(16) float va[Hn];
  __shared__ float sc_s[64];
  __shared__ float wgt[64];
  __shared__ float cbuf[Hn];
  const int b = blockIdx.x, tid = threadIdx.x;
  if (tid < Hn) { qv[tid] = qb_g[b * Hn + tid]; va[tid] = Va_w[tid]; }
  __syncthreads();
  // scores: s = tid>>4 (0..63), 16 lanes per s, coalesced stride-16 over k
  {
    const int s = tid >> 4, j = tid & 15;
    const float* kprow = &kp[((size_t)b * Sn + s) * Hn];
    float a = 0.f;
#pragma unroll 4
    for (int kk = 0; kk < 32; kk++) {
      int k = kk * 16 + j;
      a += tanh_fast(qv[k] + kprow[k]) * va[k];
    }
#pragma unroll
    for (int off = 1; off < 16; off <<= 1) a += __shfl_xor(a, off);
    if (j == 0) sc_s[s] = a + Va_b[0];
  }
  __syncthreads();
  if (tid < 64) {
    float v = sc_s[tid], m = v;
    for (int off = 32; off; off >>= 1) m = fmaxf(m, __shfl_xor(m, off));
    float e = __expf(v - m), ss = e;
    for (int off = 32; off; off >>= 1) ss += __shfl_xor(ss, off);
    float w = e / ss;
    wgt[tid] = w;
    attn_out[((size_t)b * Tn + t) * Sn + tid] = w;
  }
  __syncthreads();
  // context: col = tid&511, 2-way s-split
  {
    const int col = tid & 511, sh = tid >> 9;
    float a = 0.f;
#pragma unroll 4
    for (int s5 = 0; s5 < 32; s5++) {
      int s = sh * 32 + s5;
      a += wgt[s] * enc[((size_t)b * Sn + s) * Hn + col];
    }
    if (sh == 0) cbuf[col] = a;
    __syncthreads();
    if (sh == 1) ctx[b * Hn + col] = a + cbuf[col];
  }
}

// ---------------- GRU: 64 blocks x 768 (thread = gate x i x b) ----------------
__global__ void __launch_bounds__(768) gru_kernel(const float* __restrict__ emb,
                                                  const int* __restrict__ tok,
                                                  const float* __restrict__ ctx,
                                                  const float* __restrict__ h_cur,
                                                  const float* __restrict__ W_ih,
                                                  const float* __restrict__ W_hh,
                                                  const float* __restrict__ b_ih,
                                                  const float* __restrict__ b_hh,
                                                  float* __restrict__ h_nxt) {
  __shared__ __align__(16) float ch[32][132];
  __shared__ float s_rz[2][8][32];
  __shared__ float s_n[8][32];
  __shared__ float s_hn[8][32];
  __shared__ int tks[32];
  const int tid = threadIdx.x;
  const int b = tid & 31, i_l = (tid >> 5) & 7, g = tid >> 8;   // g in 0..2
  const int i0 = blockIdx.x * 8;
  const int ig = i0 + i_l;
  const int row = g * Hn + ig;                                   // gate-row in [0,1536)
  if (tid < 32) tks[tid] = tok[tid];
  const float4* wi = (const float4*)&W_ih[(size_t)row * (Hn + Hn)];
  const float4* wh = (const float4*)&W_hh[(size_t)row * Hn];
  float acc_i = 0.f, acc_h = 0.f;
  // gi: K=1024 (x || ctx) in 8 chunks of 128
  for (int c = 0; c < 8; c++) {
    const int k0 = c * 128;
    __syncthreads();
    for (int f = tid; f < 4096; f += 768) {
      int bb = f >> 7, kk = f & 127;
      ch[bb][kk] = (c < 4) ? emb[(size_t)tks[bb] * Hn + k0 + kk]
                           : ctx[bb * Hn + (k0 - Hn) + kk];
    }
    __syncthreads();
    const float4* cb = (const float4*)&ch[b][0];
#pragma unroll
    for (int k4 = 0; k4 < 32; k4++)
      acc_i += dot4(wi[c * 32 + k4], cb[k4]);
  }
  // gh: K=512 in 4 chunks
  for (int c = 0; c < 4; c++) {
    const int k0 = c * 128;
    __syncthreads();
    for (int f = tid; f < 4096; f += 768) {
      int bb = f >> 7, kk = f & 127;
      ch[bb][kk] = h_cur[bb * Hn + k0 + kk];
    }
    __syncthreads();
    const float4* cb = (const float4*)&ch[b][0];
#pragma unroll
    for (int k4 = 0; k4 < 32; k4++)
      acc_h += dot4(wh[c * 32 + k4], cb[k4]);
  }
  const float pre = acc_i + b_ih[row];
  const float ph  = acc_h + b_hh[row];
  if (g < 2) s_rz[g][i_l][b] = pre + ph;
  else { s_n[i_l][b] = pre; s_hn[i_l][b] = ph; }
  __syncthreads();
  if (tid < 256) {
    const int bb = tid & 31, ii = tid >> 5;
    const float r = sigmoid_fast(s_rz[0][ii][bb]);
    const float z = sigmoid_fast(s_rz[1][ii][bb]);
    const float n = tanh_fast(s_n[ii][bb] + r * s_hn[ii][bb]);
    const int igg = i0 + ii;
    const float hv = h_cur[bb * Hn + igg];
    h_nxt[bb * Hn + igg] = (1.f - z) * n + z * hv;
  }
}

// ---------------- logits + argmax + fused q_{t+1}. 500 blocks x 512 ----------------
__global__ void __launch_bounds__(512) logits_kernel(const float* __restrict__ h_new,
                                                     const float* __restrict__ out_w,
                                                     const float* __restrict__ out_b,
                                                     const float* __restrict__ Wa_w,
                                                     const float* __restrict__ Wa_b,
                                                     float* __restrict__ qnext,
                                                     float* __restrict__ logits_out,
                                                     unsigned long long* __restrict__ packed,
                                                     int* __restrict__ tok,
                                                     unsigned int* __restrict__ done,
                                                     int t) {
  __shared__ __align__(16) float hc[32][132];
  __shared__ float redm[32][17];
  __shared__ int   redi[32][17];
  __shared__ float qred[256];
  __shared__ unsigned int rank;
  const int tid = threadIdx.x;
  const int b = tid & 31, vg = tid >> 5;       // vg 0..15
  const int v0 = blockIdx.x * 64;
  const int vr = v0 + vg * 4;
  const bool bq = (blockIdx.x < 64);
  const int qrh = (tid >> 5) & 7;              // q row-in-block
  const int qkh = tid >> 8;                    // q k-half
  const int qr  = blockIdx.x * 8 + qrh;        // q row (blocks<64 cover 512 rows)
  float acc0 = 0.f, acc1 = 0.f, acc2 = 0.f, acc3 = 0.f;
  float qa = 0.f;
  const float4* w0 = (const float4*)&out_w[(size_t)(vr + 0) * Hn];
  const float4* w1 = (const float4*)&out_w[(size_t)(vr + 1) * Hn];
  const float4* w2 = (const float4*)&out_w[(size_t)(vr + 2) * Hn];
  const float4* w3 = (const float4*)&out_w[(size_t)(vr + 3) * Hn];
  const float4* wq = (const float4*)&Wa_w[(size_t)qr * Hn];
  for (int c = 0; c < 4; c++) {
    const int k0 = c * 128;
    __syncthreads();
#pragma unroll
    for (int r = 0; r < 8; r++) {
      int f = tid + r * 512; int bb = f >> 7, kk = f & 127;
      hc[bb][kk] = h_new[bb * Hn + k0 + kk];
    }
    __syncthreads();
    const float4* cb = (const float4*)&hc[b][0];
#pragma unroll
    for (int k4 = 0; k4 < 32; k4++) {
      float4 x = cb[k4];
      acc0 += dot4(w0[c * 32 + k4], x);
      acc1 += dot4(w1[c * 32 + k4], x);
      acc2 += dot4(w2[c * 32 + k4], x);
      acc3 += dot4(w3[c * 32 + k4], x);
    }
    if (bq) {
#pragma unroll
      for (int k4 = 0; k4 < 16; k4++)
        qa += dot4(wq[c * 32 + qkh * 16 + k4], cb[qkh * 16 + k4]);
    }
  }
  // epilogue: logits store + per-thread argmax
  float x0 = acc0 + out_b[vr + 0];
  float x1 = acc1 + out_b[vr + 1];
  float x2 = acc2 + out_b[vr + 2];
  float x3 = acc3 + out_b[vr + 3];
  float4 st = make_float4(x0, x1, x2, x3);
  *(float4*)&logits_out[((size_t)b * Tn + t) * Vn + vr] = st;
  float best = x0; int bidx = vr;
  if (x1 > best) { best = x1; bidx = vr + 1; }
  if (x2 > best) { best = x2; bidx = vr + 2; }
  if (x3 > best) { best = x3; bidx = vr + 3; }
  redm[b][vg] = best; redi[b][vg] = bidx;
  if (bq && qkh == 1) qred[tid & 255] = qa;
  __syncthreads();
  if (bq && qkh == 0) qnext[b * Hn + qr] = qa + qred[tid] + Wa_b[qr];
  if (tid < 32) {
    float bst = redm[tid][0]; int bix = redi[tid][0];
#pragma unroll
    for (int g = 1; g < 16; g++)
      if (redm[tid][g] > bst) { bst = redm[tid][g]; bix = redi[tid][g]; }
    unsigned int u = __float_as_uint(bst);
    unsigned int key = (u & 0x80000000u) ? ~u : (u | 0x80000000u);
    unsigned long long pk = ((unsigned long long)key << 32) |
                            (unsigned long long)(0xFFFFFFFFu - (unsigned int)bix);
    atomicMax(&packed[t * Bn + tid], pk);
  }
  __threadfence();
  if (tid == 0) rank = atomicAdd(&done[t], 1u);
  __syncthreads();
  if (rank == gridDim.x - 1) {
    __threadfence();
    if (tid < 32) {
      unsigned long long pk = atomicAdd(&packed[t * Bn + tid], 0ull);
      tok[tid] = (int)(0xFFFFFFFFu - (unsigned int)(pk & 0xFFFFFFFFull));
    }
  }
}

// ---------------- finalize: 2-pass online log_softmax + h_last copy ----------------
__global__ void __launch_bounds__(256) finalize_kernel(float* __restrict__ out1,
                                                       const float* __restrict__ h_src,
                                                       float* __restrict__ out2) {
  if (blockIdx.x == (unsigned)(Bn * Tn)) {
    for (int i = threadIdx.x; i < Bn * Hn; i += 256) out2[i] = h_src[i];
    return;
  }
  float* row = out1 + (size_t)blockIdx.x * Vn;
  const int tid = threadIdx.x;
  __shared__ float redM[4], redL[4], s_lz;
  const float4* r4 = (const float4*)row;
  float m = -1e30f, l = 0.f;
  for (int i = tid; i < Vn / 4; i += 256) {
    float4 v = r4[i];
    float vm = fmaxf(fmaxf(v.x, v.y), fmaxf(v.z, v.w));
    float nm = fmaxf(m, vm);
    l = l * __expf(m - nm) + __expf(v.x - nm) + __expf(v.y - nm)
        + __expf(v.z - nm) + __expf(v.w - nm);
    m = nm;
  }
  for (int off = 32; off; off >>= 1) {
    float m2 = __shfl_xor(m, off), l2 = __shfl_xor(l, off);
    float nm = fmaxf(m, m2);
    l = l * __expf(m - nm) + l2 * __expf(m2 - nm);
    m = nm;
  }
  if ((tid & 63) == 0) { redM[tid >> 6] = m; redL[tid >> 6] = l; }
  __syncthreads();
  if (tid == 0) {
    float M = redM[0], L = redL[0];
    for (int w = 1; w < 4; w++) {
      float nm = fmaxf(M, redM[w]);
      L = L * __expf(M - nm) + redL[w] * __expf(redM[w] - nm);
      M = nm;
    }
    s_lz = M + __logf(L);
  }
  __syncthreads();
  const float lz = s_lz;
  float4* w4p = (float4*)row;
  for (int i = tid; i < Vn / 4; i += 256) {
    float4 v = r4[i];
    v.x -= lz; v.y -= lz; v.z -= lz; v.w -= lz;
    w4p[i] = v;
  }
}

extern "C" void kernel_launch(void* const* d_in, const int* in_sizes, int n_in,
                              void* d_out, int out_size, void* d_ws, size_t ws_size,
                              hipStream_t stream) {
  (void)in_sizes; (void)n_in; (void)out_size; (void)ws_size;
  const float* enc   = (const float*)d_in[0];
  const float* ehid  = (const float*)d_in[1];
  const float* emb   = (const float*)d_in[2];
  const float* Wa_w  = (const float*)d_in[3];
  const float* Wa_b  = (const float*)d_in[4];
  const float* Ua_w  = (const float*)d_in[5];
  const float* Ua_b  = (const float*)d_in[6];
  const float* Va_w  = (const float*)d_in[7];
  const float* Va_b  = (const float*)d_in[8];
  const float* W_ih  = (const float*)d_in[9];
  const float* W_hh  = (const float*)d_in[10];
  const float* b_ih  = (const float*)d_in[11];
  const float* b_hh  = (const float*)d_in[12];
  const float* out_w = (const float*)d_in[13];
  const float* out_b = (const float*)d_in[14];
  const int*   sos   = (const int*)d_in[15];

  float* ws    = (float*)d_ws;
  float* kp    = ws + KP_OFF;
  float* hbuf0 = ws + H0_OFF;
  float* hbuf1 = ws + H1_OFF;
  float* ctx   = ws + CTX_OFF;
  float* qbuf  = ws + QB_OFF;
  unsigned long long* packed = (unsigned long long*)(ws + PK_OFF);
  int*          tok  = (int*)(ws + TOK_OFF);
  unsigned int* done = (unsigned int*)(ws + DONE_OFF);

  float* out1 = (float*)d_out;                    // logprobs [B,T,V]
  float* out2 = out1 + (size_t)Bn * Tn * Vn;      // h_last [1,B,H]
  float* out3 = out2 + Bn * Hn;                   // attn [B,T,S]

  kp_kernel<<<dim3(64, 8), 256, 0, stream>>>(enc, Ua_w, Ua_b, kp);
  init_kernel<<<65, 256, 0, stream>>>(ehid, sos, Wa_w, Wa_b, hbuf0, qbuf, packed, tok, done);
  for (int t = 0; t < Tn; t++) {
    float* h_cur = (t & 1) ? hbuf1 : hbuf0;
    float* h_nxt = (t & 1) ? hbuf0 : hbuf1;
    attn_kernel<<<Bn, 1024, 0, stream>>>(enc, kp, Va_w, Va_b, qbuf, ctx, out3, t);
    gru_kernel<<<64, 768, 0, stream>>>(emb, tok, ctx, h_cur, W_ih, W_hh, b_ih, b_hh, h_nxt);
    logits_kernel<<<500, 512, 0, stream>>>(h_nxt, out_w, out_b, Wa_w, Wa_b, qbuf,
                                           out1, packed, tok, done, t);
  }
  finalize_kernel<<<Bn * Tn + 1, 256, 0, stream>>>(out1, hbuf0, out2);
}